// Round 4
// baseline (283.077 us; speedup 1.0000x reference)
//
#include <hip/hip_runtime.h>
#include <hip/hip_bf16.h>

// Reassociated Tucker pipeline (fp32 in/out; bf16 internally):
//   y[b,t,o] = sum_j Z[b,t,j] * M[t,j,o]
//     Z[b,t,j] = sum_i x[b,t,i]   * in_core[i,j]      <- t-independent, contiguous GEMM
//     M[t,j,o] = sum_k W1[t,j,k]  * out_core[o,k]
//     W1[t,j,k]= sum_m task[t,m]  * tensor[m,j,k]
//
// v4 resubmit (round-3 bench died to container-acquisition failure; no
// kernel signal). FUSE Z-compute and y-compute into one kernel. The
// dependency y[row,:] = Z[row,:]*M[t(row)] is row-local, so a block that owns
// 16 same-t rows never needs global Z. 3 dispatches:
//   K_SETUP : W1[t][j][k] (64 KB) + icT[j][i]=in_core^T (512 KB)
//   K2      : M_T[t][o][j] (MFMA, 4 MB)
//   K_FUSED : per block (16 rows, one t):
//             phase1: Zb[16][64] = X[rows][4096] * icT^T  (LDS-staged, swizzled)
//             phase2: y[rows][4096] = Zb * M_T[t]         (LDS-transpose epilogue)
//   t = blockIdx&7 -> round-robin dispatch puts each t on one XCD: its L2
//   holds exactly M_T[t] (512KB) + icT (512KB) for all that XCD's re-reads.

typedef __bf16 bf16;
typedef __bf16 bf16x8 __attribute__((ext_vector_type(8)));
typedef __bf16 bf16x4 __attribute__((ext_vector_type(4)));
typedef float  f32x4  __attribute__((ext_vector_type(4)));

__device__ __forceinline__ bf16x8 load_frag_bf16(const bf16* p) {
    return *reinterpret_cast<const bf16x8*>(p);
}

__device__ __forceinline__ bf16x8 load_frag_f32(const float* p) {
    f32x4 a = *reinterpret_cast<const f32x4*>(p);
    f32x4 b = *reinterpret_cast<const f32x4*>(p + 4);
    bf16x8 r;
    r[0] = (bf16)a[0]; r[1] = (bf16)a[1]; r[2] = (bf16)a[2]; r[3] = (bf16)a[3];
    r[4] = (bf16)b[0]; r[5] = (bf16)b[1]; r[6] = (bf16)b[2]; r[7] = (bf16)b[3];
    return r;
}

__device__ __forceinline__ f32x4 mfma16(bf16x8 a, bf16x8 b, f32x4 c) {
    return __builtin_amdgcn_mfma_f32_16x16x32_bf16(a, b, c, 0, 0, 0);
}

// ---------------------------------------------------------------- K_SETUP
// grid 256 x 256. Blocks 0..127: W1[t][j][k] = sum_m task[t][m]*tensor[m][j][k].
// Blocks 128..255: icT[j][i] = bf16(in_core[i][j]) (16B stores, 1KB runs).
__global__ __launch_bounds__(256) void k_setup(
    const float* __restrict__ task,    // [8][64]
    const float* __restrict__ tensor,  // [64][64][64] (m, j, k)
    const float* __restrict__ in_core, // [4096][64]   (i, j)
    bf16* __restrict__ w1,             // [8][64][64]  (t, j, k)
    bf16* __restrict__ icT)            // [64][4096]   (j, i)
{
    int bid = blockIdx.x;
    if (bid < 128) {
        int t    = bid >> 4;
        int idx  = (bid & 15) * 256 + threadIdx.x;  // 0..4095
        int j    = idx >> 6;
        int k    = idx & 63;                        // lanes consecutive in k
        float acc = 0.f;
        #pragma unroll 8
        for (int m = 0; m < 64; ++m)
            acc += task[t * 64 + m] * tensor[(m * 64 + j) * 64 + k];
        w1[(t * 64 + j) * 64 + k] = (bf16)acc;
    } else {
        int idx = (bid - 128) * 256 + threadIdx.x;  // 0..32767
        int i0  = (idx & 511) * 8;
        int j   = idx >> 9;
        bf16x8 v;
        #pragma unroll
        for (int s = 0; s < 8; ++s)
            v[s] = (bf16)in_core[(size_t)(i0 + s) * 64 + j];
        *reinterpret_cast<bf16x8*>(icT + (size_t)j * 4096 + i0) = v;
    }
}

// ---------------------------------------------------------------- K2
// grid 512 x 256. M_T[t][o][j] = sum_k out_core[o][k]*W1[t][j][k].
// Per t: M=4096(o), N=64(j), K=64. Wave: 16 o-rows x 64 j.
__global__ __launch_bounds__(256) void k2_mt(
    const float* __restrict__ out_core, // [4096][64] (o, k) fp32
    const bf16* __restrict__ w1,        // [8][64][64] (t, j, k)
    bf16* __restrict__ mt)              // [8][4096][64] (t, o, j)
{
    int t    = blockIdx.x >> 6;
    int ot   = blockIdx.x & 63;
    int wave = threadIdx.x >> 6;
    int lane = threadIdx.x & 63;
    int m    = lane & 15;
    int q    = lane >> 4;
    int o0   = ot * 64 + wave * 16;

    f32x4 acc[4] = {};
    #pragma unroll
    for (int kc = 0; kc < 64; kc += 32) {
        bf16x8 a = load_frag_f32(out_core + (size_t)(o0 + m) * 64 + kc + q * 8);
        #pragma unroll
        for (int nt = 0; nt < 4; ++nt) {
            bf16x8 b = load_frag_bf16(w1 + (size_t)(t * 64 + nt * 16 + m) * 64 + kc + q * 8);
            acc[nt] = mfma16(a, b, acc[nt]);
        }
    }
    #pragma unroll
    for (int nt = 0; nt < 4; ++nt) {
        #pragma unroll
        for (int r = 0; r < 4; ++r) {
            int o = o0 + q * 4 + r;                  // C/D row = quad*4 + reg
            mt[(size_t)(t * 4096 + o) * 64 + nt * 16 + m] = (bf16)acc[nt][r];
        }
    }
}

// ---------------------------------------------------------------- K_FUSED
// grid 512 x 256. Block: t = bid&7, rows (b0+i)*8+t for i=0..15, b0=(bid>>3)*16.
// Phase 1 (Z): BK=256 f32 x-tile staged in LDS (bf16, XOR-swizzled), depth-2
// register prefetch; per global-load instr 4 row-segments x 256B contiguous.
// Result Zb[16][64] -> LDS (padded stride 80), barrier.
// Phase 2 (y): per wave o-range = wave*1024; 8 groups of 128 o: 16 MFMA from
// L2-resident M_T[t], then wave-private LDS slab transpose -> f32x4 stores,
// 512B contiguous per row per instruction.
__global__ __launch_bounds__(256) void k_fused(
    const float* __restrict__ x,   // [8192][4096] fp32 (rows = b*8+t)
    const bf16* __restrict__ icT,  // [64][4096] (j, i)
    const bf16* __restrict__ mt,   // [8][4096][64] (t, o, j)
    float* __restrict__ y)         // [1024][8][4096] fp32
{
    __shared__ bf16  xs[16 * 256];   // 8 KB staging tile
    __shared__ bf16  zb[16 * 80];    // 2.5 KB Zb, stride 80 (16B-aligned, padded)
    __shared__ float slab[4 * 2112]; // 33 KB: 4 waves x 16 rows x stride 132

    int t    = blockIdx.x & 7;       // one t per XCD (round-robin dispatch)
    int b0   = (blockIdx.x >> 3) * 16;
    int tid  = threadIdx.x;
    int r    = tid >> 4;             // staging row 0..15
    int c16  = tid & 15;             // staging col group
    int wave = tid >> 6;
    int lane = tid & 63;
    int m    = lane & 15;
    int q    = lane >> 4;
    int n0   = wave * 16;            // j-range of this wave (phase 1)

    const float* gsrc = x   + (size_t)((b0 + r) * 8 + t) * 4096;
    const bf16*  bbas = icT + (size_t)(n0 + m) * 4096;

    // ---------------- phase 1: Zb = X[16 rows][4096] * icT^T ----------------
    f32x4 vA[4], vB[4];
    #pragma unroll
    for (int i = 0; i < 4; ++i)
        vA[i] = *reinterpret_cast<const f32x4*>(gsrc + c16 * 4 + i * 64);
    #pragma unroll
    for (int i = 0; i < 4; ++i)
        vB[i] = *reinterpret_cast<const f32x4*>(gsrc + 256 + c16 * 4 + i * 64);

    f32x4 acc = {};
    #pragma unroll 1
    for (int kc = 0; kc < 4096; kc += 512) {
        // half A: compute tile kc from vA, prefetch kc+512 into vA
        __syncthreads();             // previous tile's LDS reads done
        #pragma unroll
        for (int i = 0; i < 4; ++i) {
            bf16x4 w;
            w[0] = (bf16)vA[i][0]; w[1] = (bf16)vA[i][1];
            w[2] = (bf16)vA[i][2]; w[3] = (bf16)vA[i][3];
            int col = c16 * 4 + i * 64;
            int u   = (col >> 3) ^ (r & 7);          // XOR swizzle, 16B units
            *reinterpret_cast<bf16x4*>(&xs[r * 256 + u * 8 + (col & 7)]) = w;
        }
        __syncthreads();
        if (kc + 512 < 4096) {
            #pragma unroll
            for (int i = 0; i < 4; ++i)
                vA[i] = *reinterpret_cast<const f32x4*>(gsrc + kc + 512 + c16 * 4 + i * 64);
        }
        #pragma unroll
        for (int c = 0; c < 8; ++c) {
            int u = (c * 4 + q) ^ (m & 7);
            bf16x8 a = *reinterpret_cast<const bf16x8*>(&xs[m * 256 + u * 8]);
            bf16x8 b = load_frag_bf16(bbas + kc + c * 32 + q * 8);  // L2-resident
            acc = mfma16(a, b, acc);
        }
        // half B: compute tile kc+256 from vB, prefetch kc+768 into vB
        __syncthreads();
        #pragma unroll
        for (int i = 0; i < 4; ++i) {
            bf16x4 w;
            w[0] = (bf16)vB[i][0]; w[1] = (bf16)vB[i][1];
            w[2] = (bf16)vB[i][2]; w[3] = (bf16)vB[i][3];
            int col = c16 * 4 + i * 64;
            int u   = (col >> 3) ^ (r & 7);
            *reinterpret_cast<bf16x4*>(&xs[r * 256 + u * 8 + (col & 7)]) = w;
        }
        __syncthreads();
        if (kc + 768 < 4096) {
            #pragma unroll
            for (int i = 0; i < 4; ++i)
                vB[i] = *reinterpret_cast<const f32x4*>(gsrc + kc + 768 + c16 * 4 + i * 64);
        }
        #pragma unroll
        for (int c = 0; c < 8; ++c) {
            int u = (c * 4 + q) ^ (m & 7);
            bf16x8 a = *reinterpret_cast<const bf16x8*>(&xs[m * 256 + u * 8]);
            bf16x8 b = load_frag_bf16(bbas + kc + 256 + c * 32 + q * 8);
            acc = mfma16(a, b, acc);
        }
    }
    // acc[rr] = Z[row = q*4+rr][j = n0+m]  (D-row <-> A-row, D-col <-> B-row)
    #pragma unroll
    for (int rr = 0; rr < 4; ++rr)
        zb[(q * 4 + rr) * 80 + n0 + m] = (bf16)acc[rr];
    __syncthreads();                 // Zb complete (cross-wave j ranges)

    // ---------------- phase 2: y[16 rows][4096] = Zb * M_T[t] ----------------
    // A-frags: lane m = Z-row, q selects 8 j's within each 32-chunk. One-time load.
    bf16x8 a_lo = *reinterpret_cast<const bf16x8*>(zb + m * 80 + q * 8);
    bf16x8 a_hi = *reinterpret_cast<const bf16x8*>(zb + m * 80 + 32 + q * 8);

    float* sw = slab + wave * 2112;              // wave-private slab
    const bf16* mbase = mt + ((size_t)t * 4096 + wave * 1024) * 64;

    #pragma unroll 1
    for (int g = 0; g < 8; ++g) {
        f32x4 acc2[8] = {};
        #pragma unroll
        for (int nt = 0; nt < 8; ++nt) {
            const bf16* bp = mbase + (size_t)(g * 128 + nt * 16 + m) * 64;
            bf16x8 blo = load_frag_bf16(bp + q * 8);        // L2-resident (XCD-local)
            bf16x8 bhi = load_frag_bf16(bp + 32 + q * 8);
            acc2[nt] = mfma16(a_lo, blo, acc2[nt]);
            acc2[nt] = mfma16(a_hi, bhi, acc2[nt]);
        }
        // transpose 16 rows x 128 o through wave-private slab
        #pragma unroll
        for (int nt = 0; nt < 8; ++nt) {
            #pragma unroll
            for (int rr = 0; rr < 4; ++rr)
                sw[(q * 4 + rr) * 132 + nt * 16 + m] = acc2[nt][rr];
        }
        #pragma unroll
        for (int p = 0; p < 8; ++p) {
            int row = 2 * p + (lane >> 5);       // 2 rows x 512B contiguous / instr
            int cu  = lane & 31;
            f32x4 d = *reinterpret_cast<const f32x4*>(sw + row * 132 + cu * 4);
            *reinterpret_cast<f32x4*>(
                y + (size_t)((b0 + row) * 8 + t) * 4096 + wave * 1024 + g * 128 + cu * 4) = d;
        }
    }
}

// ----------------------------------------------------------------
extern "C" void kernel_launch(void* const* d_in, const int* in_sizes, int n_in,
                              void* d_out, int out_size, void* d_ws, size_t ws_size,
                              hipStream_t stream) {
    // setup_inputs order: x, tensor_core, task_core, in_core, out_core (all fp32)
    const float* x        = (const float*)d_in[0];
    const float* tensor_c = (const float*)d_in[1];
    const float* task_c   = (const float*)d_in[2];
    const float* in_c     = (const float*)d_in[3];
    const float* out_c    = (const float*)d_in[4];
    float* y = (float*)d_out;

    // Workspace layout (bytes): w1 64KB | icT 512KB | M_T 4MB
    char* ws = (char*)d_ws;
    bf16* w1  = (bf16*)ws;
    bf16* icT = (bf16*)(ws + (64 << 10));
    bf16* mtc = (bf16*)(ws + (64 << 10) + (512 << 10));

    k_setup<<<256, 256, 0, stream>>>(task_c, tensor_c, in_c, w1, icT);
    k2_mt  <<<512, 256, 0, stream>>>(out_c, w1, mtc);
    k_fused<<<512, 256, 0, stream>>>(x, icT, mtc, y);
}